// Round 1
// baseline (295.436 us; speedup 1.0000x reference)
//
#include <hip/hip_runtime.h>
#include <math.h>

// PHM adapter: down (768->192, n=4 rank-1 kron) -> gelu_new -> up (192->768).
// One wave per token. Lane l: a = l>>4 (kron block), r = l&15 (slot).
// Memory-bound: ~201 MB total traffic -> ~32 us floor at 6.3 TB/s.

#define SQ2PI 0.79788456080286535588f

__global__ __launch_bounds__(256, 4)
void phm_fused(const float* __restrict__ x,
               const float* __restrict__ rule_d,
               const float* __restrict__ Wl_d,
               const float* __restrict__ Wr_d,
               const float* __restrict__ bias_d,
               const float* __restrict__ rule_u,
               const float* __restrict__ Wl_u,
               const float* __restrict__ Wr_u,
               const float* __restrict__ bias_u,
               float* __restrict__ out,
               int n_tokens)
{
    // LDS weights (lane-varying addresses); <=2-way bank aliasing everywhere.
    __shared__ __attribute__((aligned(16))) float sLd[768];   // W_left_d  [i][p]   i*192+p
    __shared__ __attribute__((aligned(16))) float sLu[192];   // W_left_u  [i][q]   i*48+q
    __shared__ __attribute__((aligned(16))) float sRu[768];   // W_right_u [i][q2]  i*192+q2
    __shared__ float sRuleD[64];                              // [i][a][c] i*16+a*4+c
    __shared__ float sRuleU[64];

    const int tid = threadIdx.x;
    for (int i = tid; i < 768; i += 256) sLd[i] = Wl_d[i];
    for (int i = tid; i < 192; i += 256) sLu[i] = Wl_u[i];
    for (int i = tid; i < 768; i += 256) sRu[i] = Wr_u[i];
    if (tid < 64)                 sRuleD[tid]      = rule_d[tid];
    else if (tid < 128)           sRuleU[tid - 64] = rule_u[tid - 64];
    __syncthreads();

    const int lane = tid & 63;
    const int wave = tid >> 6;
    const int a    = lane >> 4;   // kron block 0..3 (also c for z-phase outputs)
    const int r    = lane & 15;   // slot within block

    // Per-lane-invariant weight preloads (stay in registers for all tokens).
    float bd[3];                   // bias_d at o = a*48 + 3r + w
    float rdw[4][3];               // W_right_d[i][3r+w]
    float4 bu[3];                  // bias_u at o = a*192 + 12r + 4u .. +3
    #pragma unroll
    for (int w = 0; w < 3; ++w) bd[w] = bias_d[a*48 + 3*r + w];
    #pragma unroll
    for (int i = 0; i < 4; ++i)
        #pragma unroll
        for (int w = 0; w < 3; ++w) rdw[i][w] = Wr_d[i*48 + 3*r + w];
    #pragma unroll
    for (int u = 0; u < 3; ++u)
        bu[u] = *(const float4*)(bias_u + a*192 + 12*r + 4*u);

    for (int tok = blockIdx.x*4 + wave; tok < n_tokens; tok += gridDim.x*4) {
        // ---- load my 12 x elements: block a, p = 12r .. 12r+11 ----
        const float* xt = x + (size_t)tok*768 + a*192 + 12*r;
        float4 xv[3];
        #pragma unroll
        for (int u = 0; u < 3; ++u) xv[u] = *(const float4*)(xt + 4*u);

        // ---- down dots: s[i] = partial over my 12 p's of dot(x_block_a, L_d[i]) ----
        float s[4] = {0.f, 0.f, 0.f, 0.f};
        #pragma unroll
        for (int u = 0; u < 3; ++u) {
            #pragma unroll
            for (int i = 0; i < 4; ++i) {
                const float4 lv = *(const float4*)(&sLd[i*192 + 12*r + 4*u]);
                s[i] = fmaf(xv[u].x, lv.x, s[i]);
                s[i] = fmaf(xv[u].y, lv.y, s[i]);
                s[i] = fmaf(xv[u].z, lv.z, s[i]);
                s[i] = fmaf(xv[u].w, lv.w, s[i]);
            }
        }
        // reduce within group of 16 (group is 16-aligned, xor<16 stays inside)
        #pragma unroll
        for (int i = 0; i < 4; ++i)
            #pragma unroll
            for (int off = 1; off < 16; off <<= 1)
                s[i] += __shfl_xor(s[i], off);

        // gather s[i][a'] from every group
        float sA[4][4];
        #pragma unroll
        for (int aa = 0; aa < 4; ++aa)
            #pragma unroll
            for (int i = 0; i < 4; ++i)
                sA[i][aa] = __shfl(s[i], aa*16 + r);

        // t[i] for my c == a: t = sum_aa sA[i][aa] * rule_d[i][aa][a]
        float tD[4];
        #pragma unroll
        for (int i = 0; i < 4; ++i) {
            float acc = 0.f;
            #pragma unroll
            for (int aa = 0; aa < 4; ++aa)
                acc = fmaf(sA[i][aa], sRuleD[i*16 + aa*4 + a], acc);
            tD[i] = acc;
        }

        // ---- z + gelu at o = a*48 + 3r + w  (exactly the elems I need next) ----
        float g[3];
        #pragma unroll
        for (int w = 0; w < 3; ++w) {
            float z = bd[w];
            #pragma unroll
            for (int i = 0; i < 4; ++i) z = fmaf(tD[i], rdw[i][w], z);
            const float inner = SQ2PI * fmaf(0.044715f*z, z*z, z);
            const float e  = __expf(2.0f*inner);          // tanh(y)=1-2/(e^{2y}+1)
            const float th = 1.0f - 2.0f/(e + 1.0f);
            g[w] = 0.5f*z*(1.0f + th);
        }

        // ---- up dots: block a2 == a, q = 3r+w ----
        float p[4] = {0.f, 0.f, 0.f, 0.f};
        #pragma unroll
        for (int w = 0; w < 3; ++w) {
            const int q = 3*r + w;
            #pragma unroll
            for (int i = 0; i < 4; ++i)
                p[i] = fmaf(g[w], sLu[i*48 + q], p[i]);
        }
        #pragma unroll
        for (int i = 0; i < 4; ++i)
            #pragma unroll
            for (int off = 1; off < 16; off <<= 1)
                p[i] += __shfl_xor(p[i], off);

        float sA2[4][4];
        #pragma unroll
        for (int aa = 0; aa < 4; ++aa)
            #pragma unroll
            for (int i = 0; i < 4; ++i)
                sA2[i][aa] = __shfl(p[i], aa*16 + r);

        float tU[4];
        #pragma unroll
        for (int i = 0; i < 4; ++i) {
            float acc = 0.f;
            #pragma unroll
            for (int aa = 0; aa < 4; ++aa)
                acc = fmaf(sA2[i][aa], sRuleU[i*16 + aa*4 + a], acc);
            tU[i] = acc;
        }

        // ---- output: o = a*192 + 12r + 4u + k, q2 = 12r + 4u + k ----
        float* ot = out + (size_t)tok*768 + a*192 + 12*r;
        #pragma unroll
        for (int u = 0; u < 3; ++u) {
            float4 ov = bu[u];
            #pragma unroll
            for (int i = 0; i < 4; ++i) {
                const float4 ru = *(const float4*)(&sRu[i*192 + 12*r + 4*u]);
                ov.x = fmaf(tU[i], ru.x, ov.x);
                ov.y = fmaf(tU[i], ru.y, ov.y);
                ov.z = fmaf(tU[i], ru.z, ov.z);
                ov.w = fmaf(tU[i], ru.w, ov.w);
            }
            *(float4*)(ot + 4*u) = ov;
        }
    }
}

extern "C" void kernel_launch(void* const* d_in, const int* in_sizes, int n_in,
                              void* d_out, int out_size, void* d_ws, size_t ws_size,
                              hipStream_t stream) {
    const float* x      = (const float*)d_in[0];
    const float* rule_d = (const float*)d_in[1];
    const float* Wl_d   = (const float*)d_in[2];
    const float* Wr_d   = (const float*)d_in[3];
    const float* bias_d = (const float*)d_in[4];
    const float* rule_u = (const float*)d_in[5];
    const float* Wl_u   = (const float*)d_in[6];
    const float* Wr_u   = (const float*)d_in[7];
    const float* bias_u = (const float*)d_in[8];
    float* out          = (float*)d_out;

    const int n_tokens = in_sizes[0] / 768;   // 32768

    phm_fused<<<dim3(1024), dim3(256), 0, stream>>>(
        x, rule_d, Wl_d, Wr_d, bias_d, rule_u, Wl_u, Wr_u, bias_u, out, n_tokens);
}

// Round 2
// 205.052 us; speedup vs baseline: 1.4408x; 1.4408x over previous
//
#include <hip/hip_runtime.h>
#include <math.h>

// PHM adapter: down (768->192, n=4 rank-1 kron) -> gelu_new -> up (192->768).
// Round 2: stage tokens through LDS so ALL global accesses are per-instruction
// coalesced (tid-linear float4). Round-1 counters showed 2.7x HBM amplification
// from 48B-stride float4 accesses (partial-line fetch + store RMW).
// Compute core identical to round 1 (passed, absmax 1.5e-8):
//   one wave per token; lane l: a=l>>4 (kron block), r=l&15; lane owns the
//   12 floats at [a*192+12r, +12) for both input and output.

#define SQ2PI 0.79788456080286535588f
#define T_TILE 8   // tokens per block-iteration; 8*768*4B = 24 KB tile

__global__ __launch_bounds__(256, 4)
void phm_fused(const float* __restrict__ x,
               const float* __restrict__ rule_d,
               const float* __restrict__ Wl_d,
               const float* __restrict__ Wr_d,
               const float* __restrict__ bias_d,
               const float* __restrict__ rule_u,
               const float* __restrict__ Wl_u,
               const float* __restrict__ Wr_u,
               const float* __restrict__ bias_u,
               float* __restrict__ out,
               int n_tokens)
{
    __shared__ __attribute__((aligned(16))) float sTile[T_TILE * 768]; // 24 KB, in-place in/out
    __shared__ __attribute__((aligned(16))) float sLd[768];   // W_left_d  [i][p]   i*192+p
    __shared__ __attribute__((aligned(16))) float sLu[192];   // W_left_u  [i][q]   i*48+q
    __shared__ __attribute__((aligned(16))) float sRu[768];   // W_right_u [i][q2]  i*192+q2
    __shared__ float sRuleD[64];                              // [i][a][c] i*16+a*4+c
    __shared__ float sRuleU[64];

    const int tid = threadIdx.x;
    for (int i = tid; i < 768; i += 256) sLd[i] = Wl_d[i];
    for (int i = tid; i < 192; i += 256) sLu[i] = Wl_u[i];
    for (int i = tid; i < 768; i += 256) sRu[i] = Wr_u[i];
    if (tid < 64)       sRuleD[tid]      = rule_d[tid];
    else if (tid < 128) sRuleU[tid - 64] = rule_u[tid - 64];

    const int lane = tid & 63;
    const int wave = tid >> 6;
    const int a    = lane >> 4;   // kron block 0..3 (also c for z-phase outputs)
    const int r    = lane & 15;   // slot within block

    // Per-lane-invariant weight preloads (registers, all tokens).
    float bd[3];                   // bias_d at o = a*48 + 3r + w
    float rdw[4][3];               // W_right_d[i][3r+w]
    float4 bu[3];                  // bias_u at o = a*192 + 12r + 4u .. +3
    #pragma unroll
    for (int w = 0; w < 3; ++w) bd[w] = bias_d[a*48 + 3*r + w];
    #pragma unroll
    for (int i = 0; i < 4; ++i)
        #pragma unroll
        for (int w = 0; w < 3; ++w) rdw[i][w] = Wr_d[i*48 + 3*r + w];
    #pragma unroll
    for (int u = 0; u < 3; ++u)
        bu[u] = *(const float4*)(bias_u + a*192 + 12*r + 4*u);
    __syncthreads();

    const long long total4 = (long long)n_tokens * 192;   // total float4 count
    const int n_tiles = (n_tokens + T_TILE - 1) / T_TILE;

    for (int tile = blockIdx.x; tile < n_tiles; tile += gridDim.x) {
        const long long g4 = (long long)tile * (T_TILE * 192);

        // ---- cooperative coalesced stage: 1536 float4 / 256 threads = 6 each ----
        #pragma unroll
        for (int j = 0; j < (T_TILE * 192) / 256; ++j) {
            const int idx = tid + j * 256;
            const long long gi = g4 + idx;
            float4 v = make_float4(0.f, 0.f, 0.f, 0.f);
            if (gi < total4) v = *(const float4*)(x + gi * 4);
            *(float4*)&sTile[idx * 4] = v;
        }
        __syncthreads();

        // ---- compute: each wave owns T_TILE/4 tokens, in-place in sTile ----
        #pragma unroll
        for (int s = 0; s < T_TILE / 4; ++s) {
            const int tloc = wave * (T_TILE / 4) + s;
            const int tok  = tile * T_TILE + tloc;
            if (tok < n_tokens) {
                float* xt = &sTile[tloc * 768 + a * 192 + 12 * r];
                float4 xv[3];
                #pragma unroll
                for (int u = 0; u < 3; ++u) xv[u] = *(const float4*)(xt + 4 * u);

                // down dots: s_i = partial over my 12 p's of dot(x_block_a, L_d[i])
                float sd[4] = {0.f, 0.f, 0.f, 0.f};
                #pragma unroll
                for (int u = 0; u < 3; ++u) {
                    #pragma unroll
                    for (int i = 0; i < 4; ++i) {
                        const float4 lv = *(const float4*)(&sLd[i*192 + 12*r + 4*u]);
                        sd[i] = fmaf(xv[u].x, lv.x, sd[i]);
                        sd[i] = fmaf(xv[u].y, lv.y, sd[i]);
                        sd[i] = fmaf(xv[u].z, lv.z, sd[i]);
                        sd[i] = fmaf(xv[u].w, lv.w, sd[i]);
                    }
                }
                #pragma unroll
                for (int i = 0; i < 4; ++i)
                    #pragma unroll
                    for (int off = 1; off < 16; off <<= 1)
                        sd[i] += __shfl_xor(sd[i], off);

                float sA[4][4];
                #pragma unroll
                for (int aa = 0; aa < 4; ++aa)
                    #pragma unroll
                    for (int i = 0; i < 4; ++i)
                        sA[i][aa] = __shfl(sd[i], aa*16 + r);

                float tD[4];
                #pragma unroll
                for (int i = 0; i < 4; ++i) {
                    float acc = 0.f;
                    #pragma unroll
                    for (int aa = 0; aa < 4; ++aa)
                        acc = fmaf(sA[i][aa], sRuleD[i*16 + aa*4 + a], acc);
                    tD[i] = acc;
                }

                // z + gelu at o = a*48 + 3r + w
                float g[3];
                #pragma unroll
                for (int w = 0; w < 3; ++w) {
                    float z = bd[w];
                    #pragma unroll
                    for (int i = 0; i < 4; ++i) z = fmaf(tD[i], rdw[i][w], z);
                    const float inner = SQ2PI * fmaf(0.044715f*z, z*z, z);
                    const float e  = __expf(2.0f*inner);      // tanh(y)=1-2/(e^{2y}+1)
                    const float th = 1.0f - 2.0f/(e + 1.0f);
                    g[w] = 0.5f*z*(1.0f + th);
                }

                // up dots
                float p[4] = {0.f, 0.f, 0.f, 0.f};
                #pragma unroll
                for (int w = 0; w < 3; ++w) {
                    const int q = 3*r + w;
                    #pragma unroll
                    for (int i = 0; i < 4; ++i)
                        p[i] = fmaf(g[w], sLu[i*48 + q], p[i]);
                }
                #pragma unroll
                for (int i = 0; i < 4; ++i)
                    #pragma unroll
                    for (int off = 1; off < 16; off <<= 1)
                        p[i] += __shfl_xor(p[i], off);

                float sA2[4][4];
                #pragma unroll
                for (int aa = 0; aa < 4; ++aa)
                    #pragma unroll
                    for (int i = 0; i < 4; ++i)
                        sA2[i][aa] = __shfl(p[i], aa*16 + r);

                float tU[4];
                #pragma unroll
                for (int i = 0; i < 4; ++i) {
                    float acc = 0.f;
                    #pragma unroll
                    for (int aa = 0; aa < 4; ++aa)
                        acc = fmaf(sA2[i][aa], sRuleU[i*16 + aa*4 + a], acc);
                    tU[i] = acc;
                }

                // output chunk back IN PLACE (lane overwrites exactly what it read)
                #pragma unroll
                for (int u = 0; u < 3; ++u) {
                    float4 ov = bu[u];
                    #pragma unroll
                    for (int i = 0; i < 4; ++i) {
                        const float4 ru = *(const float4*)(&sRu[i*192 + 12*r + 4*u]);
                        ov.x = fmaf(tU[i], ru.x, ov.x);
                        ov.y = fmaf(tU[i], ru.y, ov.y);
                        ov.z = fmaf(tU[i], ru.z, ov.z);
                        ov.w = fmaf(tU[i], ru.w, ov.w);
                    }
                    *(float4*)(xt + 4 * u) = ov;
                }
            }
        }
        __syncthreads();

        // ---- cooperative coalesced store ----
        #pragma unroll
        for (int j = 0; j < (T_TILE * 192) / 256; ++j) {
            const int idx = tid + j * 256;
            const long long gi = g4 + idx;
            if (gi < total4)
                *(float4*)(out + gi * 4) = *(const float4*)&sTile[idx * 4];
        }
        __syncthreads();   // protect sTile before next tile's staging
    }
}

extern "C" void kernel_launch(void* const* d_in, const int* in_sizes, int n_in,
                              void* d_out, int out_size, void* d_ws, size_t ws_size,
                              hipStream_t stream) {
    const float* x      = (const float*)d_in[0];
    const float* rule_d = (const float*)d_in[1];
    const float* Wl_d   = (const float*)d_in[2];
    const float* Wr_d   = (const float*)d_in[3];
    const float* bias_d = (const float*)d_in[4];
    const float* rule_u = (const float*)d_in[5];
    const float* Wl_u   = (const float*)d_in[6];
    const float* Wr_u   = (const float*)d_in[7];
    const float* bias_u = (const float*)d_in[8];
    float* out          = (float*)d_out;

    const int n_tokens = in_sizes[0] / 768;   // 32768

    phm_fused<<<dim3(1024), dim3(256), 0, stream>>>(
        x, rule_d, Wl_d, Wr_d, bias_d, rule_u, Wl_u, Wr_u, bias_u, out, n_tokens);
}